// Round 6
// baseline (1681.744 us; speedup 1.0000x reference)
//
#include <hip/hip_runtime.h>

#define LOG2E 1.4426950408889634f

typedef _Float16 h2t __attribute__((ext_vector_type(2)));

// broadcast lane `srclane`'s value to all lanes via v_readlane (SGPR result).
__device__ __forceinline__ float rl(float v, int srclane) {
  return __int_as_float(__builtin_amdgcn_readlane(__float_as_int(v), srclane));
}
__device__ __forceinline__ unsigned rlu(unsigned v, int srclane) {
  return (unsigned)__builtin_amdgcn_readlane((int)v, srclane);
}
__device__ __forceinline__ float rfl(float v) {
  return __int_as_float(__builtin_amdgcn_readfirstlane(__float_as_int(v)));
}

// quad broadcast via DPP quad_perm
template<int CTL>
__device__ __forceinline__ float qb(float v) {
  return __int_as_float(__builtin_amdgcn_update_dpp(0, __float_as_int(v), CTL, 0xF, 0xF, true));
}

__device__ __forceinline__ float fast_rcp(float x)  { return __builtin_amdgcn_rcpf(x); }
__device__ __forceinline__ float fast_exp2(float x) { return __builtin_amdgcn_exp2f(x); }

__device__ __forceinline__ float sigf(float x) {
  return fast_rcp(1.0f + fast_exp2(-LOG2E * x));
}
__device__ __forceinline__ float tanhfast(float x) {
  return fmaf(fast_rcp(1.0f + fast_exp2(-2.0f * LOG2E * x)), 2.0f, -1.0f);
}

#if defined(__has_builtin)
#if __has_builtin(__builtin_amdgcn_fdot2)
#define USE_FDOT2 1
#endif
#endif

// one LSTM recurrence step for one chain (lane layout: r = g*16+j, g=lane&3).
// hpk holds the f16 pair (h_{2p}, h_{2p+1}) valid on lanes 8p (packed last step).
__device__ __forceinline__ void lstm_step(float pre, const h2t* __restrict__ w2,
                                          float amul, float aadd,
                                          unsigned& hpk, float& ct, float& h) {
  const unsigned q0 = rlu(hpk,  0);
  const unsigned q1 = rlu(hpk,  8);
  const unsigned q2 = rlu(hpk, 16);
  const unsigned q3 = rlu(hpk, 24);
  const unsigned q4 = rlu(hpk, 32);
  const unsigned q5 = rlu(hpk, 40);
  const unsigned q6 = rlu(hpk, 48);
  const unsigned q7 = rlu(hpk, 56);
#if defined(USE_FDOT2)
  float a0 = pre, a1 = 0.f;
  a0 = __builtin_amdgcn_fdot2(__builtin_bit_cast(h2t, q0), w2[0], a0, false);
  a1 = __builtin_amdgcn_fdot2(__builtin_bit_cast(h2t, q4), w2[4], a1, false);
  a0 = __builtin_amdgcn_fdot2(__builtin_bit_cast(h2t, q1), w2[1], a0, false);
  a1 = __builtin_amdgcn_fdot2(__builtin_bit_cast(h2t, q5), w2[5], a1, false);
  a0 = __builtin_amdgcn_fdot2(__builtin_bit_cast(h2t, q2), w2[2], a0, false);
  a1 = __builtin_amdgcn_fdot2(__builtin_bit_cast(h2t, q6), w2[6], a1, false);
  a0 = __builtin_amdgcn_fdot2(__builtin_bit_cast(h2t, q3), w2[3], a0, false);
  a1 = __builtin_amdgcn_fdot2(__builtin_bit_cast(h2t, q7), w2[7], a1, false);
  const float m = a0 + a1;                        // = -ksc * preact
#else
  h2t aA = {(_Float16)0, (_Float16)0};
  h2t aB = {(_Float16)0, (_Float16)0};
  aA = __builtin_elementwise_fma(__builtin_bit_cast(h2t, q0), w2[0], aA);
  aB = __builtin_elementwise_fma(__builtin_bit_cast(h2t, q4), w2[4], aB);
  aA = __builtin_elementwise_fma(__builtin_bit_cast(h2t, q1), w2[1], aA);
  aB = __builtin_elementwise_fma(__builtin_bit_cast(h2t, q5), w2[5], aB);
  aA = __builtin_elementwise_fma(__builtin_bit_cast(h2t, q2), w2[2], aA);
  aB = __builtin_elementwise_fma(__builtin_bit_cast(h2t, q6), w2[6], aB);
  aA = __builtin_elementwise_fma(__builtin_bit_cast(h2t, q3), w2[3], aA);
  aB = __builtin_elementwise_fma(__builtin_bit_cast(h2t, q7), w2[7], aB);
  aA = aA + aB;
  const float m = (pre + (float)aA.x) + (float)aA.y;
#endif
  const float e   = fast_exp2(m);
  const float sgm = fast_rcp(1.0f + e);           // sigmoid(ksc'*P)
  const float act = fmaf(sgm, amul, aadd);        // sigmoid / -2log2e*tanh
  const float fa = qb<0x55>(act);
  const float ga = qb<0xAA>(act);                 // = -2log2e * g
  const float oa = qb<0xFF>(act);
  ct = fmaf(fa, ct, act * ga);                    // act == ia on g=0 lanes
  const float e2 = fast_exp2(ct);
  const float tc = fmaf(fast_rcp(1.0f + e2), 2.0f, -1.0f);   // tanh(c)
  h = oa * tc;
  // pack f16 pair (same DPP pattern as R5 — correctness-proven)
  const int hpart = __builtin_amdgcn_update_dpp(
      0, __float_as_int(h), 0x104, 0xF, 0xF, true);
  hpk = __builtin_bit_cast(unsigned,
      __builtin_amdgcn_cvt_pkrtz(h, __int_as_float(hpart)));
}

// One bidirectional-LSTM layer, BOTH directions per block (software-interleaved
// in one consumer wave: chain B's instructions fill chain A's dependency stalls
// — a lone in-order wave can't fill them any other way; R5 showed 285 cyc/step
// with only ~44% VALU busy).
// grid = 128 (one per batch b), block = 256 (4 waves):
//   wave0: consumer — both recurrences interleaved.
//   wave1: producer dir0 xW ring; wave2: producer dir1 xW ring.
//   wave3: drains both h rings (2 slots behind) to global.
template<int IN, bool LAST>
__global__ __launch_bounds__(256, 1) void bilstm_layer(
    const float* __restrict__ x,     // (B,T,IN)
    const float* __restrict__ Wih,   // (2,64,IN)
    const float* __restrict__ Whh,   // (2,64,16)
    const float* __restrict__ bias,  // (2,64)
    float* __restrict__ out)         // (B,T,32) or (B,256,32) if LAST
{
  constexpr int T = 2048;
  constexpr int C = 64;          // ring chunk (steps)
  constexpr int NCH = T / C;
  constexpr int NSLOT = NCH + 2; // xW produce -> consume -> h drain
  constexpr int NV4 = IN / 4;
  const int b    = blockIdx.x;
  const int tid  = threadIdx.x;
  const int wave = tid >> 6;
  const int lane = tid & 63;
  const int g = lane & 3;
  const int r = g * 16 + (lane >> 2);
  const float ksc = (g == 2) ? 2.0f * LOG2E : LOG2E;

  // split per-dir so each object stays < 64 KB; total 131 KB (fits 160 KB/CU)
  __shared__ float ringX0[2][(C + 2) * 64];
  __shared__ float ringX1[2][(C + 2) * 64];
  __shared__ float ringH0[2][C * 65];
  __shared__ float ringH1[2][C * 65];

  if (wave == 1 || wave == 2) {
    // ---------------- xW producer for dir = wave-1 ----------------
    const int dir = wave - 1;
    float wih[IN];
    const float* wr = Wih + (size_t)(dir * 64 + r) * IN;
#pragma unroll
    for (int k = 0; k < IN; ++k) wih[k] = -ksc * wr[k];
    const float bneg = -ksc * bias[dir * 64 + r];
    const float* xb = x + (size_t)b * T * IN;
    for (int c = 0; c < NSLOT; ++c) {
      if (c < NCH) {
        const int tt0  = c * C;
        const int tmin = dir ? (T - C - tt0) : tt0;
        const float* src = xb + (size_t)(tmin + lane) * IN;
        float4 xr[NV4];
#pragma unroll
        for (int v = 0; v < NV4; ++v) xr[v] = *(const float4*)(src + 4 * v);
        float* buf = dir ? ringX1[c & 1] : ringX0[c & 1];
        for (int s = 0; s < C; ++s) {
          const int row = dir ? (C - 1 - s) : s;
          float a0 = bneg, a1 = 0.0f;
#pragma unroll
          for (int v = 0; v < NV4; ++v) {
            a0 = fmaf(rl(xr[v].x, row), wih[4 * v + 0], a0);
            a1 = fmaf(rl(xr[v].y, row), wih[4 * v + 1], a1);
            a0 = fmaf(rl(xr[v].z, row), wih[4 * v + 2], a0);
            a1 = fmaf(rl(xr[v].w, row), wih[4 * v + 3], a1);
          }
          buf[s * 64 + lane] = a0 + a1;   // = -ksc*(Wih·x_t + b)
        }
      }
      __syncthreads();
    }
  } else if (wave == 3) {
    // ---------------- h drain (both dirs), 2 slots behind ----------------
    const int sl = lane >> 4;    // step sub-row 0..3
    const int jj = lane & 15;    // hidden index
    for (int c = 0; c < NSLOT; ++c) {
      if (c >= 2 && c - 2 < NCH) {
        const int d = c - 2;
#pragma unroll
        for (int dir = 0; dir < 2; ++dir) {
          const float* r2 = dir ? ringH1[d & 1] : ringH0[d & 1];
          for (int s0 = 0; s0 < C; s0 += 4) {
            const int s  = s0 + sl;
            const float hv = r2[s * 65 + 4 * jj];
            const int tt = d * C + s;
            const int t  = dir ? (T - 1 - tt) : tt;
            if (!LAST) {
              out[((size_t)b * T + t) * 32 + dir * 16 + jj] = hv;
            } else if ((t & 7) == 7) {
              out[((size_t)b * 256 + (t >> 3)) * 32 + dir * 16 + jj] = hv;
            }
          }
        }
      }
      __syncthreads();
    }
  } else {
    // ---------------- consumer: both recurrences interleaved ----------------
    h2t w2A[8], w2B[8];
    {
      const float* wrA = Whh + (size_t)(0 * 64 + r) * 16;
      const float* wrB = Whh + (size_t)(1 * 64 + r) * 16;
#pragma unroll
      for (int p = 0; p < 8; ++p) {
        h2t wa, wb;
        wa.x = (_Float16)(-ksc * wrA[2 * p]);
        wa.y = (_Float16)(-ksc * wrA[2 * p + 1]);
        wb.x = (_Float16)(-ksc * wrB[2 * p]);
        wb.y = (_Float16)(-ksc * wrB[2 * p + 1]);
        w2A[p] = wa; w2B[p] = wb;
      }
    }
    const float amul = (g == 2) ? -4.0f * LOG2E : 1.0f;
    const float aadd = (g == 2) ?  2.0f * LOG2E : 0.0f;
    float ctA = 0.f, hA = 0.f, ctB = 0.f, hB = 0.f;
    unsigned hpkA = 0, hpkB = 0;
    for (int c = 0; c < NSLOT; ++c) {
      if (c >= 1 && c <= NCH) {
        const float* bpA = (c - 1) & 1 ? ringX0[1] : ringX0[0]; bpA += lane;
        const float* bpB = (c - 1) & 1 ? ringX1[1] : ringX1[0]; bpB += lane;
        float* hbA = ((c - 1) & 1 ? ringH0[1] : ringH0[0]) + lane;
        float* hbB = ((c - 1) & 1 ? ringH1[1] : ringH1[0]) + lane;
        float pA0 = bpA[0], pA1 = bpA[64];
        float pB0 = bpB[0], pB1 = bpB[64];
#pragma unroll 2
        for (int s = 0; s < C; ++s) {
          const float pA2 = bpA[(s + 2) * 64];   // distance-2 prefetch (+2 pad rows)
          const float pB2 = bpB[(s + 2) * 64];
          lstm_step(pA0, w2A, amul, aadd, hpkA, ctA, hA);
          lstm_step(pB0, w2B, amul, aadd, hpkB, ctB, hB);
          hbA[s * 65] = hA;
          hbB[s * 65] = hB;
          pA0 = pA1; pA1 = pA2;
          pB0 = pB1; pB1 = pB2;
        }
      }
      __syncthreads();
    }
  }
}

// Precompute layer-0 xW for the unidirectional stack: xw0[b][t][g] = ub0[g] + uWih0[g]·x
__global__ __launch_bounds__(256) void uni_xw0(
    const float* __restrict__ dsb,    // (B,256,32)
    const float* __restrict__ uWih0,  // (4,32)
    const float* __restrict__ ub,     // (4,4) — row 0 used
    float* __restrict__ xw0)          // (B,256,4)
{
  const int b = blockIdx.x;
  const int t = threadIdx.x;
  const float* xp = dsb + ((size_t)b * 256 + t) * 32;
  float xv[32];
#pragma unroll
  for (int k = 0; k < 32; k += 4) {
    const float4 v = *(const float4*)(xp + k);
    xv[k] = v.x; xv[k + 1] = v.y; xv[k + 2] = v.z; xv[k + 3] = v.w;
  }
  float4 o;
  float* po = &o.x;
#pragma unroll
  for (int gg = 0; gg < 4; ++gg) {
    float a0 = ub[gg], a1 = 0.f;
#pragma unroll
    for (int k = 0; k < 32; k += 2) {
      a0 = fmaf(uWih0[gg * 32 + k],     xv[k],     a0);
      a1 = fmaf(uWih0[gg * 32 + k + 1], xv[k + 1], a1);
    }
    po[gg] = a0 + a1;
  }
  *(float4*)(xw0 + ((size_t)b * 256 + t) * 4) = o;
}

// Fused 4-layer unidirectional stack (HU=1), step-synchronous across layers.
__global__ __launch_bounds__(64, 1) void uni_stack(
    const float* __restrict__ xw0,   // (B,256,4) pre-biased layer-0 xW
    const float* __restrict__ uWih,  // (3,4,1)
    const float* __restrict__ uWhh,  // (4,4,1)
    const float* __restrict__ ub,    // (4,4)
    float* __restrict__ out)         // (B,256)
{
  const int b = blockIdx.x * 64 + threadIdx.x;
  float whh[4][4], wih[3][4], bs[3][4];
#pragma unroll
  for (int l = 0; l < 4; ++l)
#pragma unroll
    for (int gg = 0; gg < 4; ++gg) whh[l][gg] = rfl(uWhh[l * 4 + gg]);
#pragma unroll
  for (int l = 0; l < 3; ++l)
#pragma unroll
    for (int gg = 0; gg < 4; ++gg) {
      wih[l][gg] = rfl(uWih[l * 4 + gg]);
      bs[l][gg]  = rfl(ub[(l + 1) * 4 + gg]);
    }
  float h[4] = {0, 0, 0, 0}, c[4] = {0, 0, 0, 0};
  const float4* xp = (const float4*)(xw0 + (size_t)b * 256 * 4);
  float* op = out + (size_t)b * 256;
  float4 cur = xp[0];
  for (int t = 0; t < 256; ++t) {
    const float4 nxt = xp[(t < 255) ? (t + 1) : 255];   // prefetch (guarded)
    {
      const float i0 = sigf(fmaf(whh[0][0], h[0], cur.x));
      const float f0 = sigf(fmaf(whh[0][1], h[0], cur.y));
      const float g0 = tanhfast(fmaf(whh[0][2], h[0], cur.z));
      const float o0 = sigf(fmaf(whh[0][3], h[0], cur.w));
      c[0] = fmaf(f0, c[0], i0 * g0);
      h[0] = o0 * tanhfast(c[0]);
    }
#pragma unroll
    for (int l = 1; l < 4; ++l) {
      const float xin = h[l - 1];
      const float pi  = fmaf(whh[l][0], h[l], fmaf(wih[l - 1][0], xin, bs[l - 1][0]));
      const float pf  = fmaf(whh[l][1], h[l], fmaf(wih[l - 1][1], xin, bs[l - 1][1]));
      const float pg  = fmaf(whh[l][2], h[l], fmaf(wih[l - 1][2], xin, bs[l - 1][2]));
      const float po_ = fmaf(whh[l][3], h[l], fmaf(wih[l - 1][3], xin, bs[l - 1][3]));
      const float il = sigf(pi), fl = sigf(pf), gl = tanhfast(pg), ol = sigf(po_);
      c[l] = fmaf(fl, c[l], il * gl);
      h[l] = ol * tanhfast(c[l]);
    }
    op[t] = h[3];
    cur = nxt;
  }
}

extern "C" void kernel_launch(void* const* d_in, const int* in_sizes, int n_in,
                              void* d_out, int out_size, void* d_ws, size_t ws_size,
                              hipStream_t stream)
{
  (void)in_sizes; (void)n_in; (void)out_size; (void)ws_size;
  const float* r_c_s = (const float*)d_in[0];
  const float* bWih0 = (const float*)d_in[1];
  const float* bWih  = (const float*)d_in[2];
  const float* bWhh  = (const float*)d_in[3];
  const float* bb    = (const float*)d_in[4];
  const float* uWih0 = (const float*)d_in[5];
  const float* uWih  = (const float*)d_in[6];
  const float* uWhh  = (const float*)d_in[7];
  const float* ub    = (const float*)d_in[8];
  float* outp = (float*)d_out;

  // workspace layout (floats): two (B,T,32) ping-pong, (B,256,32) downsample, (B,256,4) uni-xW
  float* x0  = (float*)d_ws;
  float* x1  = x0  + (size_t)128 * 2048 * 32;
  float* dsb = x1  + (size_t)128 * 2048 * 32;
  float* xw0 = dsb + (size_t)128 * 256 * 32;

  const dim3 grid(128), block(256);
  bilstm_layer<24, false><<<grid, block, 0, stream>>>(r_c_s, bWih0,               bWhh + 0,               bb + 0,          x0);
  bilstm_layer<32, false><<<grid, block, 0, stream>>>(x0,    bWih + 0 * 2*64*32,  bWhh + 1 * 2*64*16,     bb + 1 * 2*64,   x1);
  bilstm_layer<32, false><<<grid, block, 0, stream>>>(x1,    bWih + 1 * 2*64*32,  bWhh + 2 * 2*64*16,     bb + 2 * 2*64,   x0);
  bilstm_layer<32, true ><<<grid, block, 0, stream>>>(x0,    bWih + 2 * 2*64*32,  bWhh + 3 * 2*64*16,     bb + 3 * 2*64,   dsb);
  uni_xw0 <<<dim3(128), dim3(256), 0, stream>>>(dsb, uWih0, ub, xw0);
  uni_stack<<<dim3(2),   dim3(64),  0, stream>>>(xw0, uWih, uWhh, ub, outp);
}

// Round 7
// 1050.178 us; speedup vs baseline: 1.6014x; 1.6014x over previous
//
#include <hip/hip_runtime.h>

#define LOG2E 1.4426950408889634f

typedef _Float16 h2t __attribute__((ext_vector_type(2)));

// broadcast lane `srclane`'s value to all lanes via v_readlane (SGPR result).
__device__ __forceinline__ float rl(float v, int srclane) {
  return __int_as_float(__builtin_amdgcn_readlane(__float_as_int(v), srclane));
}
__device__ __forceinline__ unsigned rlu(unsigned v, int srclane) {
  return (unsigned)__builtin_amdgcn_readlane((int)v, srclane);
}
__device__ __forceinline__ float rfl(float v) {
  return __int_as_float(__builtin_amdgcn_readfirstlane(__float_as_int(v)));
}

// quad broadcast via DPP quad_perm
template<int CTL>
__device__ __forceinline__ float qb(float v) {
  return __int_as_float(__builtin_amdgcn_update_dpp(0, __float_as_int(v), CTL, 0xF, 0xF, true));
}

__device__ __forceinline__ float fast_rcp(float x)  { return __builtin_amdgcn_rcpf(x); }
__device__ __forceinline__ float fast_exp2(float x) { return __builtin_amdgcn_exp2f(x); }

__device__ __forceinline__ float sigf(float x) {
  return fast_rcp(1.0f + fast_exp2(-LOG2E * x));
}
__device__ __forceinline__ float tanhfast(float x) {
  return fmaf(fast_rcp(1.0f + fast_exp2(-2.0f * LOG2E * x)), 2.0f, -1.0f);
}

#if defined(__has_builtin)
#if __has_builtin(__builtin_amdgcn_fdot2)
#define USE_FDOT2 1
#endif
#endif

// one LSTM recurrence step (lane layout: r = g*16+j, g=lane&3).
// hpk holds the f16 pair (h_{2p}, h_{2p+1}) valid on lanes 8p (packed last step).
__device__ __forceinline__ void lstm_step(float pre, const h2t* __restrict__ w2,
                                          float amul, float aadd,
                                          unsigned& hpk, float& ct, float& h) {
  const unsigned q0 = rlu(hpk,  0);
  const unsigned q1 = rlu(hpk,  8);
  const unsigned q2 = rlu(hpk, 16);
  const unsigned q3 = rlu(hpk, 24);
  const unsigned q4 = rlu(hpk, 32);
  const unsigned q5 = rlu(hpk, 40);
  const unsigned q6 = rlu(hpk, 48);
  const unsigned q7 = rlu(hpk, 56);
#if defined(USE_FDOT2)
  float a0 = pre, a1 = 0.f;
  a0 = __builtin_amdgcn_fdot2(__builtin_bit_cast(h2t, q0), w2[0], a0, false);
  a1 = __builtin_amdgcn_fdot2(__builtin_bit_cast(h2t, q4), w2[4], a1, false);
  a0 = __builtin_amdgcn_fdot2(__builtin_bit_cast(h2t, q1), w2[1], a0, false);
  a1 = __builtin_amdgcn_fdot2(__builtin_bit_cast(h2t, q5), w2[5], a1, false);
  a0 = __builtin_amdgcn_fdot2(__builtin_bit_cast(h2t, q2), w2[2], a0, false);
  a1 = __builtin_amdgcn_fdot2(__builtin_bit_cast(h2t, q6), w2[6], a1, false);
  a0 = __builtin_amdgcn_fdot2(__builtin_bit_cast(h2t, q3), w2[3], a0, false);
  a1 = __builtin_amdgcn_fdot2(__builtin_bit_cast(h2t, q7), w2[7], a1, false);
  const float m = a0 + a1;                        // = -ksc * preact
#else
  h2t aA = {(_Float16)0, (_Float16)0};
  h2t aB = {(_Float16)0, (_Float16)0};
  aA = __builtin_elementwise_fma(__builtin_bit_cast(h2t, q0), w2[0], aA);
  aB = __builtin_elementwise_fma(__builtin_bit_cast(h2t, q4), w2[4], aB);
  aA = __builtin_elementwise_fma(__builtin_bit_cast(h2t, q1), w2[1], aA);
  aB = __builtin_elementwise_fma(__builtin_bit_cast(h2t, q5), w2[5], aB);
  aA = __builtin_elementwise_fma(__builtin_bit_cast(h2t, q2), w2[2], aA);
  aB = __builtin_elementwise_fma(__builtin_bit_cast(h2t, q6), w2[6], aB);
  aA = __builtin_elementwise_fma(__builtin_bit_cast(h2t, q3), w2[3], aA);
  aB = __builtin_elementwise_fma(__builtin_bit_cast(h2t, q7), w2[7], aB);
  aA = aA + aB;
  const float m = (pre + (float)aA.x) + (float)aA.y;
#endif
  const float e   = fast_exp2(m);
  const float sgm = fast_rcp(1.0f + e);           // sigmoid(ksc'*P)
  const float act = fmaf(sgm, amul, aadd);        // sigmoid / -2log2e*tanh
  const float fa = qb<0x55>(act);
  const float ga = qb<0xAA>(act);                 // = -2log2e * g
  const float oa = qb<0xFF>(act);
  ct = fmaf(fa, ct, act * ga);                    // act == ia on g=0 lanes
  const float e2 = fast_exp2(ct);
  const float tc = fmaf(fast_rcp(1.0f + e2), 2.0f, -1.0f);   // tanh(c)
  h = oa * tc;
  // pack f16 pair (h_self, h_lane+4): row_shl:4 + pkrtz
  const int hpart = __builtin_amdgcn_update_dpp(
      0, __float_as_int(h), 0x104, 0xF, 0xF, true);
  hpk = __builtin_bit_cast(unsigned,
      __builtin_amdgcn_cvt_pkrtz(h, __int_as_float(hpart)));
}

// One bidirectional-LSTM layer. grid = 256 blocks (b*2+dir), block = 192 (3 waves).
// One chain per consumer wave (R6 lesson: consolidation can't win — 256 chains,
// 256 CUs; only per-step latency matters).
// Ring layout [sgroup][lane][4]: 1 ds_read_b128 / ds_write_b128 per 4 steps on
// the consumer instead of per-step dword ops.
// Wave 0: consumer. Waves 1,2: phase A produce xW (wave1: groups 0-7, wave2:
// 8-15); phase B drain h of chunk c-2 to global.
template<int IN, bool LAST>
__global__ __launch_bounds__(192, 1) void bilstm_layer(
    const float* __restrict__ x,     // (B,T,IN)
    const float* __restrict__ Wih,   // (2,64,IN)
    const float* __restrict__ Whh,   // (2,64,16)
    const float* __restrict__ bias,  // (2,64)
    float* __restrict__ out)         // (B,T,32) or (B,256,32) if LAST
{
  constexpr int T = 2048;
  constexpr int C = 64;          // ring chunk (steps)
  constexpr int NG = C / 4;      // groups per chunk (16)
  constexpr int NCH = T / C;
  constexpr int NSLOT = NCH + 2; // xW produce -> consume -> h drain
  constexpr int NV4 = IN / 4;
  const int b    = blockIdx.x >> 1;
  const int dir  = blockIdx.x & 1;
  const int tid  = threadIdx.x;
  const int wave = tid >> 6;
  const int lane = tid & 63;
  const int g = lane & 3;
  const int r = g * 16 + (lane >> 2);
  const float ksc = (g == 2) ? 2.0f * LOG2E : LOG2E;

  __shared__ float ring [2][(NG + 1) * 256];  // xW staging (+1 group: pad for prefetch)
  __shared__ float ring2[2][NG * 256];        // h staging (consumer -> drainers)

  if (wave >= 1) {
    // ---------------- producers ----------------
    const int pw = wave - 1;
    float wih[IN];
    const float* wr = Wih + (size_t)(dir * 64 + r) * IN;
#pragma unroll
    for (int k = 0; k < IN; ++k) wih[k] = -ksc * wr[k];
    const float bneg = -ksc * bias[dir * 64 + r];
    const float* xb = x + (size_t)b * T * IN;
    const int sl = lane >> 4;    // h-drain: step sub-index 0..3
    const int jj = lane & 15;    // h-drain: hidden index
    for (int c = 0; c < NSLOT; ++c) {
      // phase A: produce xW(chunk c), groups [pw*8, pw*8+8)
      if (c < NCH) {
        const int tt0  = c * C;
        const int tmin = dir ? (T - C - tt0) : tt0;
        const float* src = xb + (size_t)(tmin + lane) * IN;
        float4 xr[NV4];
#pragma unroll
        for (int v = 0; v < NV4; ++v) xr[v] = *(const float4*)(src + 4 * v);
        float* buf = ring[c & 1] + lane * 4;
        for (int mg = pw * 8; mg < pw * 8 + 8; ++mg) {
          float4 acc4;
          float* ap = &acc4.x;
#pragma unroll
          for (int u = 0; u < 4; ++u) {
            const int s   = mg * 4 + u;
            const int row = dir ? (C - 1 - s) : s;
            float a0 = bneg, a1 = 0.0f;
#pragma unroll
            for (int v = 0; v < NV4; ++v) {
              a0 = fmaf(rl(xr[v].x, row), wih[4 * v + 0], a0);
              a1 = fmaf(rl(xr[v].y, row), wih[4 * v + 1], a1);
              a0 = fmaf(rl(xr[v].z, row), wih[4 * v + 2], a0);
              a1 = fmaf(rl(xr[v].w, row), wih[4 * v + 3], a1);
            }
            ap[u] = a0 + a1;   // = -ksc*(Wih·x_t + b)
          }
          *(float4*)(buf + mg * 256) = acc4;        // ds_write_b128
        }
      }
      // phase B: drain h(chunk c-2) to global
      if (c >= 2 && c - 2 < NCH) {
        const int d = c - 2;
        const float* r2 = ring2[d & 1];
        for (int s0 = pw * 32; s0 < pw * 32 + 32; s0 += 4) {
          const int s  = s0 + sl;
          const float hv = r2[(s >> 2) * 256 + 16 * jj + (s & 3)];
          const int tt = d * C + s;
          const int t  = dir ? (T - 1 - tt) : tt;
          if (!LAST) {
            out[((size_t)b * T + t) * 32 + dir * 16 + jj] = hv;
          } else if ((t & 7) == 7) {
            out[((size_t)b * 256 + (t >> 3)) * 32 + dir * 16 + jj] = hv;
          }
        }
      }
      __syncthreads();
    }
  } else {
    // ---------------- consumer (recurrence) ----------------
    h2t w2[8];
    {
      const float* wr = Whh + (size_t)(dir * 64 + r) * 16;
#pragma unroll
      for (int p = 0; p < 8; ++p) {
        h2t w;
        w.x = (_Float16)(-ksc * wr[2 * p]);
        w.y = (_Float16)(-ksc * wr[2 * p + 1]);
        w2[p] = w;
      }
    }
    const float amul = (g == 2) ? -4.0f * LOG2E : 1.0f;
    const float aadd = (g == 2) ?  2.0f * LOG2E : 0.0f;
    float ct = 0.0f, h = 0.0f;
    unsigned hpk = 0;
    for (int c = 0; c < NSLOT; ++c) {
      if (c >= 1 && c <= NCH) {
        const float* bp = ring [(c - 1) & 1] + lane * 4;
        float*       hb = ring2[(c - 1) & 1] + lane * 4;
        float4 cur = *(const float4*)(bp);          // group 0
        for (int mg = 0; mg < NG; ++mg) {
          const float4 nxt = *(const float4*)(bp + (mg + 1) * 256);  // pad group: safe
          float4 hv4;
          lstm_step(cur.x, w2, amul, aadd, hpk, ct, h); hv4.x = h;
          lstm_step(cur.y, w2, amul, aadd, hpk, ct, h); hv4.y = h;
          lstm_step(cur.z, w2, amul, aadd, hpk, ct, h); hv4.z = h;
          lstm_step(cur.w, w2, amul, aadd, hpk, ct, h); hv4.w = h;
          *(float4*)(hb + mg * 256) = hv4;          // ds_write_b128
          cur = nxt;
        }
      }
      __syncthreads();
    }
  }
}

// Precompute layer-0 xW for the unidirectional stack: xw0[b][t][g] = ub0[g] + uWih0[g]·x
__global__ __launch_bounds__(256) void uni_xw0(
    const float* __restrict__ dsb,    // (B,256,32)
    const float* __restrict__ uWih0,  // (4,32)
    const float* __restrict__ ub,     // (4,4) — row 0 used
    float* __restrict__ xw0)          // (B,256,4)
{
  const int b = blockIdx.x;
  const int t = threadIdx.x;
  const float* xp = dsb + ((size_t)b * 256 + t) * 32;
  float xv[32];
#pragma unroll
  for (int k = 0; k < 32; k += 4) {
    const float4 v = *(const float4*)(xp + k);
    xv[k] = v.x; xv[k + 1] = v.y; xv[k + 2] = v.z; xv[k + 3] = v.w;
  }
  float4 o;
  float* po = &o.x;
#pragma unroll
  for (int gg = 0; gg < 4; ++gg) {
    float a0 = ub[gg], a1 = 0.f;
#pragma unroll
    for (int k = 0; k < 32; k += 2) {
      a0 = fmaf(uWih0[gg * 32 + k],     xv[k],     a0);
      a1 = fmaf(uWih0[gg * 32 + k + 1], xv[k + 1], a1);
    }
    po[gg] = a0 + a1;
  }
  *(float4*)(xw0 + ((size_t)b * 256 + t) * 4) = o;
}

// Fused 4-layer unidirectional stack (HU=1), software-pipelined: iteration i
// steps l0@t=i, l1@t=i-1, l2@t=i-2, l3@t=i-3 — the 4 chains are independent
// within an iteration (each consumes the PREVIOUS iteration's upstream h),
// giving 4-way ILP in one wave. lane = batch element.
__global__ __launch_bounds__(64, 1) void uni_stack(
    const float* __restrict__ xw0,   // (B,256,4) pre-biased layer-0 xW
    const float* __restrict__ uWih,  // (3,4,1)
    const float* __restrict__ uWhh,  // (4,4,1)
    const float* __restrict__ ub,    // (4,4)
    float* __restrict__ out)         // (B,256)
{
  const int b = blockIdx.x * 64 + threadIdx.x;
  float whh[4][4], wih[3][4], bs[3][4];
#pragma unroll
  for (int l = 0; l < 4; ++l)
#pragma unroll
    for (int gg = 0; gg < 4; ++gg) whh[l][gg] = rfl(uWhh[l * 4 + gg]);
#pragma unroll
  for (int l = 0; l < 3; ++l)
#pragma unroll
    for (int gg = 0; gg < 4; ++gg) {
      wih[l][gg] = rfl(uWih[l * 4 + gg]);
      bs[l][gg]  = rfl(ub[(l + 1) * 4 + gg]);
    }
  float h[4] = {0, 0, 0, 0}, c[4] = {0, 0, 0, 0};
  const float4* xp = (const float4*)(xw0 + (size_t)b * 256 * 4);
  float* op = out + (size_t)b * 256;
  for (int i = 0; i < 256 + 3; ++i) {
    const float h0p = h[0], h1p = h[1], h2p = h[2];  // previous-iteration values
    if (i < 256) {
      const float4 xw = xp[i];
      const float i0 = sigf(fmaf(whh[0][0], h[0], xw.x));
      const float f0 = sigf(fmaf(whh[0][1], h[0], xw.y));
      const float g0 = tanhfast(fmaf(whh[0][2], h[0], xw.z));
      const float o0 = sigf(fmaf(whh[0][3], h[0], xw.w));
      c[0] = fmaf(f0, c[0], i0 * g0);
      h[0] = o0 * tanhfast(c[0]);
    }
    if (i >= 1 && i < 257) {
      const float pi  = fmaf(whh[1][0], h[1], fmaf(wih[0][0], h0p, bs[0][0]));
      const float pf  = fmaf(whh[1][1], h[1], fmaf(wih[0][1], h0p, bs[0][1]));
      const float pg  = fmaf(whh[1][2], h[1], fmaf(wih[0][2], h0p, bs[0][2]));
      const float po_ = fmaf(whh[1][3], h[1], fmaf(wih[0][3], h0p, bs[0][3]));
      const float il = sigf(pi), fl = sigf(pf), gl = tanhfast(pg), ol = sigf(po_);
      c[1] = fmaf(fl, c[1], il * gl);
      h[1] = ol * tanhfast(c[1]);
    }
    if (i >= 2 && i < 258) {
      const float pi  = fmaf(whh[2][0], h[2], fmaf(wih[1][0], h1p, bs[1][0]));
      const float pf  = fmaf(whh[2][1], h[2], fmaf(wih[1][1], h1p, bs[1][1]));
      const float pg  = fmaf(whh[2][2], h[2], fmaf(wih[1][2], h1p, bs[1][2]));
      const float po_ = fmaf(whh[2][3], h[2], fmaf(wih[1][3], h1p, bs[1][3]));
      const float il = sigf(pi), fl = sigf(pf), gl = tanhfast(pg), ol = sigf(po_);
      c[2] = fmaf(fl, c[2], il * gl);
      h[2] = ol * tanhfast(c[2]);
    }
    if (i >= 3) {
      const float pi  = fmaf(whh[3][0], h[3], fmaf(wih[2][0], h2p, bs[2][0]));
      const float pf  = fmaf(whh[3][1], h[3], fmaf(wih[2][1], h2p, bs[2][1]));
      const float pg  = fmaf(whh[3][2], h[3], fmaf(wih[2][2], h2p, bs[2][2]));
      const float po_ = fmaf(whh[3][3], h[3], fmaf(wih[2][3], h2p, bs[2][3]));
      const float il = sigf(pi), fl = sigf(pf), gl = tanhfast(pg), ol = sigf(po_);
      c[3] = fmaf(fl, c[3], il * gl);
      h[3] = ol * tanhfast(c[3]);
      op[i - 3] = h[3];
    }
  }
}

extern "C" void kernel_launch(void* const* d_in, const int* in_sizes, int n_in,
                              void* d_out, int out_size, void* d_ws, size_t ws_size,
                              hipStream_t stream)
{
  (void)in_sizes; (void)n_in; (void)out_size; (void)ws_size;
  const float* r_c_s = (const float*)d_in[0];
  const float* bWih0 = (const float*)d_in[1];
  const float* bWih  = (const float*)d_in[2];
  const float* bWhh  = (const float*)d_in[3];
  const float* bb    = (const float*)d_in[4];
  const float* uWih0 = (const float*)d_in[5];
  const float* uWih  = (const float*)d_in[6];
  const float* uWhh  = (const float*)d_in[7];
  const float* ub    = (const float*)d_in[8];
  float* outp = (float*)d_out;

  // workspace layout (floats): two (B,T,32) ping-pong, (B,256,32) downsample, (B,256,4) uni-xW
  float* x0  = (float*)d_ws;
  float* x1  = x0  + (size_t)128 * 2048 * 32;
  float* dsb = x1  + (size_t)128 * 2048 * 32;
  float* xw0 = dsb + (size_t)128 * 256 * 32;

  const dim3 grid(256), block(192);
  bilstm_layer<24, false><<<grid, block, 0, stream>>>(r_c_s, bWih0,               bWhh + 0,               bb + 0,          x0);
  bilstm_layer<32, false><<<grid, block, 0, stream>>>(x0,    bWih + 0 * 2*64*32,  bWhh + 1 * 2*64*16,     bb + 1 * 2*64,   x1);
  bilstm_layer<32, false><<<grid, block, 0, stream>>>(x1,    bWih + 1 * 2*64*32,  bWhh + 2 * 2*64*16,     bb + 2 * 2*64,   x0);
  bilstm_layer<32, true ><<<grid, block, 0, stream>>>(x0,    bWih + 2 * 2*64*32,  bWhh + 3 * 2*64*16,     bb + 3 * 2*64,   dsb);
  uni_xw0 <<<dim3(128), dim3(256), 0, stream>>>(dsb, uWih0, ub, xw0);
  uni_stack<<<dim3(2),   dim3(64),  0, stream>>>(xw0, uWih, uWhh, ub, outp);
}